// Round 6
// baseline (229.665 us; speedup 1.0000x reference)
//
#include <hip/hip_runtime.h>
#include <hip/hip_bf16.h>

// Problem constants
constexpr int B  = 4;
constexpr int E  = 1024;
constexpr int Wn = 2048;
constexpr int H  = 16;
constexpr int Dh = 64;   // E / H

typedef short bf16x8 __attribute__((ext_vector_type(8)));
typedef float f32x4  __attribute__((ext_vector_type(4)));

__device__ inline unsigned short f2bf(float f){
    unsigned int u = __builtin_bit_cast(unsigned int, f);
    u = (u + 0x7fffu + ((u >> 16) & 1u)) >> 16;   // RNE
    return (unsigned short)u;
}
__device__ inline float bf2f(unsigned short u){
    return __builtin_bit_cast(float, (unsigned int)u << 16);
}
__device__ inline unsigned int pack_bf16_trunc(float lo, float hi){
    return __builtin_amdgcn_perm(__builtin_bit_cast(unsigned int, hi),
                                 __builtin_bit_cast(unsigned int, lo), 0x07060302u);
}
__device__ inline float exp2_fast(float x){ return __builtin_amdgcn_exp2f(x); }

// ---------------------------------------------------------------------------
// K0: x -> xdi (bf16, columns permuted inside each 32-block for single-MFMA PV)
// ---------------------------------------------------------------------------
__global__ void k_vint(const float* __restrict__ x, unsigned short* __restrict__ xdi){
    int tid = blockIdx.x*256 + threadIdx.x;     // [row(12) | g(8)]
    int g   = tid & 255;
    int row = tid >> 8;
    int kgw = g & 3;
    int kv0 = (g >> 2) << 5;
    const float* src = x + (size_t)row*Wn + kv0 + 4*kgw;
    float4 a = *reinterpret_cast<const float4*>(src);
    float4 b = *reinterpret_cast<const float4*>(src + 16);
    union { unsigned short us[8]; uint4 v; } u;
    u.us[0]=f2bf(a.x); u.us[1]=f2bf(a.y); u.us[2]=f2bf(a.z); u.us[3]=f2bf(a.w);
    u.us[4]=f2bf(b.x); u.us[5]=f2bf(b.y); u.us[6]=f2bf(b.z); u.us[7]=f2bf(b.w);
    *reinterpret_cast<uint4*>(xdi + (size_t)row*Wn + kv0 + 8*kgw) = u.v;
}

// ---------------------------------------------------------------------------
// K1: x -> xT (K operand, unscaled) and xQ (Q operand, scaled E^-0.5*log2e)
// ---------------------------------------------------------------------------
__global__ void k_xT(const float* __restrict__ x, unsigned short* __restrict__ xT,
                     unsigned short* __restrict__ xQ){
    const float qs = 0.03125f * 1.44269504088896340736f;
    int tid = blockIdx.x*256 + threadIdx.x;
    int w   = tid & (Wn-1);
    int dg  = (tid >> 11) & 7;
    int bh  = tid >> 14;
    const float* src = x + ((size_t)bh*Dh + dg*8)*Wn + w;
    union { unsigned short us[8]; uint4 v; } u, uq;
    #pragma unroll
    for (int i = 0; i < 8; i++){
        float f = src[(size_t)i*Wn];
        u.us[i]  = f2bf(f);
        uq.us[i] = f2bf(f * qs);
    }
    size_t off = ((size_t)bh*Wn + w)*Dh + dg*8;
    *reinterpret_cast<uint4*>(xT + off) = u.v;
    *reinterpret_cast<uint4*>(xQ + off) = uq.v;
}

// ---------------------------------------------------------------------------
// K2: M_d -> MT (bf16 transposed)
// ---------------------------------------------------------------------------
__global__ void k_MT(const float* __restrict__ M, unsigned short* __restrict__ MT){
    int tid = blockIdx.x*256 + threadIdx.x;  // [eg(7) | f(10)]
    int f  = tid & (E-1);
    int eg = tid >> 10;
    union { unsigned short us[8]; uint4 v; } u;
    #pragma unroll
    for (int i = 0; i < 8; i++) u.us[i] = f2bf(M[(size_t)(eg*8+i)*E + f]);
    *reinterpret_cast<uint4*>(MT + (size_t)f*E + eg*8) = u.v;
}

// ---------------------------------------------------------------------------
// K3: flash attention, no max-tracking -> partials are purely additive, so
// heavy q-blocks (qb>=32) are KV-SPLIT into two chunks whose (acc,l) partials
// are combined by k_reduce. 96 work-items/head, all trips <= 32, dispatched
// heavy-first: 6144 balanced waves (vs 4096 triangular before).
//   bid <  32      : heavy qb=32+bid, chunk0 kv[0,1024), partial half 0
//   bid odd  33..95: light qb=31-k (k=(bid-32)>>1), full kv, writes tws
//   bid even 32..94: heavy qb=63-k, chunk1 kv[1024,q0+32), partial half 1
// Block = 4 waves = same bid, 4 consecutive heads (equal trips, no barriers).
// ---------------------------------------------------------------------------
__global__ __launch_bounds__(256) void k_attn(const unsigned short* __restrict__ xT,
                                              const unsigned short* __restrict__ xQ,
                                              const unsigned short* __restrict__ xdi,
                                              unsigned short* __restrict__ tws,
                                              unsigned short* __restrict__ pacc,
                                              float* __restrict__ pl){
    const int lane = threadIdx.x & 63;
    const int wv   = threadIdx.x >> 6;
    const int jl = lane & 15, kg = lane >> 4;
    const int bid = blockIdx.x >> 4;                // 0..95
    const int hg  = blockIdx.x & 15;
    const int bh  = hg*4 + wv;

    int qb, kvb, kve, half;
    bool diag, heavy;
    if (bid < 32){
        qb = 32 + bid; kvb = 0; kve = 1024; diag = false; heavy = true; half = 0;
    } else {
        int k = (bid - 32) >> 1;
        if (bid & 1){ qb = 31 - k; kvb = 0;    kve = qb*32; diag = true; heavy = false; half = 0; }
        else        { qb = 63 - k; kvb = 1024; kve = qb*32; diag = true; heavy = true;  half = 1; }
    }
    const int q0 = qb*32;

    const bf16x8* xTr = reinterpret_cast<const bf16x8*>(xT + (size_t)bh*Wn*Dh);
    const bf16x8* xQr = reinterpret_cast<const bf16x8*>(xQ + (size_t)bh*Wn*Dh);
    const bf16x8* xdr = reinterpret_cast<const bf16x8*>(xdi + (size_t)bh*Dh*Wn);

    bf16x8 bq[2][2];
    #pragma unroll
    for (int jt = 0; jt < 2; jt++){
        bq[jt][0] = xQr[(q0+jt*16+jl)*8 + kg];
        bq[jt][1] = xQr[(q0+jt*16+jl)*8 + 4 + kg];
    }

    f32x4 acc[2][4] = {};
    float l[2] = {0.f, 0.f};

    // ---- interior steps (no causal mask)
    for (int kv0 = kvb; kv0 < kve; kv0 += 32){
        bf16x8 ak0a = xTr[(kv0+jl)*8 + kg];
        bf16x8 ak0b = xTr[(kv0+jl)*8 + 4 + kg];
        bf16x8 ak1a = xTr[(kv0+16+jl)*8 + kg];
        bf16x8 ak1b = xTr[(kv0+16+jl)*8 + 4 + kg];
        bf16x8 av[4];
        #pragma unroll
        for (int dt = 0; dt < 4; dt++)
            av[dt] = xdr[(dt*16+jl)*(Wn/8) + (kv0 >> 3) + kg];

        #pragma unroll
        for (int jt = 0; jt < 2; jt++){
            f32x4 s0 = {0,0,0,0}, s1 = {0,0,0,0};
            s0 = __builtin_amdgcn_mfma_f32_16x16x32_bf16(ak0a, bq[jt][0], s0, 0,0,0);
            s0 = __builtin_amdgcn_mfma_f32_16x16x32_bf16(ak0b, bq[jt][1], s0, 0,0,0);
            s1 = __builtin_amdgcn_mfma_f32_16x16x32_bf16(ak1a, bq[jt][0], s1, 0,0,0);
            s1 = __builtin_amdgcn_mfma_f32_16x16x32_bf16(ak1b, bq[jt][1], s1, 0,0,0);

            float p[8];
            #pragma unroll
            for (int r = 0; r < 4; r++){
                p[r]   = exp2_fast(s0[r]);
                p[4+r] = exp2_fast(s1[r]);
            }
            l[jt] += ((p[0]+p[1]) + (p[2]+p[3])) + ((p[4]+p[5]) + (p[6]+p[7]));

            union { bf16x8 v; unsigned int w[4]; } bp;
            bp.w[0] = pack_bf16_trunc(p[0], p[1]);
            bp.w[1] = pack_bf16_trunc(p[2], p[3]);
            bp.w[2] = pack_bf16_trunc(p[4], p[5]);
            bp.w[3] = pack_bf16_trunc(p[6], p[7]);

            #pragma unroll
            for (int dt = 0; dt < 4; dt++)
                acc[jt][dt] = __builtin_amdgcn_mfma_f32_16x16x32_bf16(av[dt], bp.v, acc[jt][dt], 0,0,0);
        }
    }

    // ---- diagonal step at kv0 = q0 (light blocks and heavy chunk1)
    if (diag){
        const int kv0 = q0;
        bf16x8 ak0a = xTr[(kv0+jl)*8 + kg];
        bf16x8 ak0b = xTr[(kv0+jl)*8 + 4 + kg];
        bf16x8 ak1a = xTr[(kv0+16+jl)*8 + kg];
        bf16x8 ak1b = xTr[(kv0+16+jl)*8 + 4 + kg];
        bf16x8 av[4];
        #pragma unroll
        for (int dt = 0; dt < 4; dt++)
            av[dt] = xdr[(dt*16+jl)*(Wn/8) + (kv0 >> 3) + kg];

        #pragma unroll
        for (int jt = 0; jt < 2; jt++){
            f32x4 s0 = {0,0,0,0}, s1 = {0,0,0,0};
            s0 = __builtin_amdgcn_mfma_f32_16x16x32_bf16(ak0a, bq[jt][0], s0, 0,0,0);
            s0 = __builtin_amdgcn_mfma_f32_16x16x32_bf16(ak0b, bq[jt][1], s0, 0,0,0);
            s1 = __builtin_amdgcn_mfma_f32_16x16x32_bf16(ak1a, bq[jt][0], s1, 0,0,0);
            s1 = __builtin_amdgcn_mfma_f32_16x16x32_bf16(ak1b, bq[jt][1], s1, 0,0,0);

            float p[8];
            #pragma unroll
            for (int r = 0; r < 4; r++){
                int c = 4*kg + r;
                float e0 = exp2_fast(s0[r]);
                float e1 = exp2_fast(s1[r]);
                p[r]   = (c      <= 16*jt + jl) ? e0 : 0.f;
                p[4+r] = (c + 16 <= 16*jt + jl) ? e1 : 0.f;
            }
            l[jt] += ((p[0]+p[1]) + (p[2]+p[3])) + ((p[4]+p[5]) + (p[6]+p[7]));

            union { bf16x8 v; unsigned int w[4]; } bp;
            bp.w[0] = pack_bf16_trunc(p[0], p[1]);
            bp.w[1] = pack_bf16_trunc(p[2], p[3]);
            bp.w[2] = pack_bf16_trunc(p[4], p[5]);
            bp.w[3] = pack_bf16_trunc(p[6], p[7]);

            #pragma unroll
            for (int dt = 0; dt < 4; dt++)
                acc[jt][dt] = __builtin_amdgcn_mfma_f32_16x16x32_bf16(av[dt], bp.v, acc[jt][dt], 0,0,0);
        }
    }

    if (!heavy){
        // ---- light epilogue: reduce l, normalize, write tws
        #pragma unroll
        for (int jt = 0; jt < 2; jt++){
            float lj = l[jt];
            lj += __shfl_xor(lj, 16);
            lj += __shfl_xor(lj, 32);
            const float inv = 1.0f / lj;
            unsigned short* trow = tws + ((size_t)(bh >> 4)*Wn + q0 + jt*16 + jl)*E + (bh & 15)*Dh;
            #pragma unroll
            for (int dt = 0; dt < 4; dt++){
                union { unsigned short us[4]; ushort4 v; } o;
                #pragma unroll
                for (int r = 0; r < 4; r++) o.us[r] = f2bf(acc[jt][dt][r] * inv);
                *reinterpret_cast<ushort4*>(trow + dt*16 + 4*kg) = o.v;
            }
        }
    } else {
        // ---- heavy epilogue: write bf16 acc partial + f32 l partial
        const int qh = qb - 32;
        const size_t slot = (size_t)(bh*32 + qh)*2 + half;
        float l0 = l[0]; l0 += __shfl_xor(l0, 16); l0 += __shfl_xor(l0, 32);
        float l1 = l[1]; l1 += __shfl_xor(l1, 16); l1 += __shfl_xor(l1, 32);
        if (kg == 0){
            pl[slot*32 + jl]      = l0;
            pl[slot*32 + 16 + jl] = l1;
        }
        unsigned short* pa = pacc + slot*2048;
        #pragma unroll
        for (int jt = 0; jt < 2; jt++){
            #pragma unroll
            for (int dt = 0; dt < 4; dt++){
                union { unsigned short us[4]; ushort4 v; } o;
                #pragma unroll
                for (int r = 0; r < 4; r++) o.us[r] = f2bf(acc[jt][dt][r]);
                *reinterpret_cast<ushort4*>(pa + (jt*16+jl)*64 + dt*16 + 4*kg) = o.v;
            }
        }
    }
}

// ---------------------------------------------------------------------------
// K3b: combine the two KV-chunk partials of each heavy q-block, normalize,
// write tws. 2048 tiles; block=256 handles 4 tiles (64 thr/tile).
// ---------------------------------------------------------------------------
__global__ __launch_bounds__(256) void k_reduce(const unsigned short* __restrict__ pacc,
                                                const float* __restrict__ pl,
                                                unsigned short* __restrict__ tws){
    const int g  = blockIdx.x*4 + (threadIdx.x >> 6);   // tile 0..2047
    const int t  = threadIdx.x & 63;
    const int bh = g >> 5, qh = g & 31;
    const int q  = t >> 1;
    const int dbase = (t & 1)*32;
    const size_t slot0 = (size_t)(bh*32 + qh)*2;

    const float inv = 1.0f / (pl[slot0*32 + q] + pl[(slot0+1)*32 + q]);
    const unsigned short* a0 = pacc + slot0*2048 + q*64 + dbase;

    unsigned short* tw = tws + ((size_t)(bh >> 4)*Wn + (qh+32)*32 + q)*E + (bh & 15)*Dh + dbase;
    #pragma unroll
    for (int i = 0; i < 4; i++){
        union { uint4 v; unsigned short us[8]; } r0, r1, o;
        r0.v = *reinterpret_cast<const uint4*>(a0 + i*8);
        r1.v = *reinterpret_cast<const uint4*>(a0 + 2048 + i*8);
        #pragma unroll
        for (int j = 0; j < 8; j++)
            o.us[j] = f2bf((bf2f(r0.us[j]) + bf2f(r1.us[j])) * inv);
        *reinterpret_cast<uint4*>(tw + i*8) = o.v;
    }
}

// ---------------------------------------------------------------------------
// K4: out[b][f][w] = sum_e MT[f][e] * t_ws[b][w][e] + b_d[f]
// ---------------------------------------------------------------------------
__global__ __launch_bounds__(256) void k_gemm(const unsigned short* __restrict__ MT,
                                              const unsigned short* __restrict__ tws,
                                              const float* __restrict__ bd,
                                              float* __restrict__ out){
    const int lane = threadIdx.x & 63;
    const int wv   = threadIdx.x >> 6;
    const int jl = lane & 15, kg = lane >> 4;
    const int blk = blockIdx.x;
    const int b  = blk >> 7;          // 128 tiles per batch
    const int t2 = blk & 127;
    const int f0 = (t2 >> 4)*128 + (wv >> 1)*64;
    const int w0 = (t2 & 15)*128 + (wv &  1)*64;

    const bf16x8* Ar = reinterpret_cast<const bf16x8*>(MT);
    const bf16x8* Br = reinterpret_cast<const bf16x8*>(tws + (size_t)b*Wn*E);

    f32x4 acc[4][4] = {};
    for (int e0 = 0; e0 < E; e0 += 32){
        bf16x8 am[4], bn[4];
        #pragma unroll
        for (int i = 0; i < 4; i++)
            am[i] = Ar[(size_t)(f0 + i*16 + jl)*(E/8) + (e0 >> 3) + kg];
        #pragma unroll
        for (int j = 0; j < 4; j++)
            bn[j] = Br[(size_t)(w0 + j*16 + jl)*(E/8) + (e0 >> 3) + kg];
        #pragma unroll
        for (int i = 0; i < 4; i++)
            #pragma unroll
            for (int j = 0; j < 4; j++)
                acc[i][j] = __builtin_amdgcn_mfma_f32_16x16x32_bf16(am[i], bn[j], acc[i][j], 0,0,0);
    }

    #pragma unroll
    for (int i = 0; i < 4; i++){
        float bias[4];
        #pragma unroll
        for (int r = 0; r < 4; r++) bias[r] = bd[f0 + i*16 + 4*kg + r];
        #pragma unroll
        for (int j = 0; j < 4; j++){
            #pragma unroll
            for (int r = 0; r < 4; r++){
                out[((size_t)b*E + f0 + i*16 + 4*kg + r)*Wn + w0 + j*16 + jl]
                    = acc[i][j][r] + bias[r];
            }
        }
    }
}

// ---------------------------------------------------------------------------
extern "C" void kernel_launch(void* const* d_in, const int* in_sizes, int n_in,
                              void* d_out, int out_size, void* d_ws, size_t ws_size,
                              hipStream_t stream) {
    const float* x  = (const float*)d_in[0];   // (B,E,W)
    const float* Md = (const float*)d_in[1];   // (E,E)
    const float* bd = (const float*)d_in[2];   // (E,)
    float* out = (float*)d_out;                // (B,E,W)

    char* ws = (char*)d_ws;
    unsigned short* xT   = (unsigned short*)(ws);                    // 16 MB
    unsigned short* xQ   = (unsigned short*)(ws + (16u << 20));      // 16 MB
    unsigned short* xdi  = (unsigned short*)(ws + (32u << 20));      // 16 MB
    unsigned short* MT   = (unsigned short*)(ws + (48u << 20));      //  2 MB
    unsigned short* tws  = (unsigned short*)(ws + (50u << 20));      // 16 MB
    float*          pl   = (float*)(ws + (66u << 20));               // 512 KB
    unsigned short* pacc = (unsigned short*)(ws + (67u << 20));      // 16 MB

    hipLaunchKernelGGL(k_vint,   dim3(4096), dim3(256), 0, stream, x, xdi);
    hipLaunchKernelGGL(k_xT,     dim3(4096), dim3(256), 0, stream, x, xT, xQ);
    hipLaunchKernelGGL(k_MT,     dim3(512),  dim3(256), 0, stream, Md, MT);
    hipLaunchKernelGGL(k_attn,   dim3(96*16), dim3(256), 0, stream, xT, xQ, xdi, tws, pacc, pl);
    hipLaunchKernelGGL(k_reduce, dim3(512),  dim3(256), 0, stream, pacc, pl, tws);
    hipLaunchKernelGGL(k_gemm,   dim3(B*(E/128)*(Wn/128)), dim3(256), 0, stream, MT, tws, bd, out);
}

// Round 7
// 228.722 us; speedup vs baseline: 1.0041x; 1.0041x over previous
//
#include <hip/hip_runtime.h>
#include <hip/hip_bf16.h>

// Problem constants
constexpr int B  = 4;
constexpr int E  = 1024;
constexpr int Wn = 2048;
constexpr int H  = 16;
constexpr int Dh = 64;   // E / H

typedef short bf16x8 __attribute__((ext_vector_type(8)));
typedef float f32x4  __attribute__((ext_vector_type(4)));

__device__ inline unsigned short f2bf(float f){
    unsigned int u = __builtin_bit_cast(unsigned int, f);
    u = (u + 0x7fffu + ((u >> 16) & 1u)) >> 16;   // RNE
    return (unsigned short)u;
}
__device__ inline float bf2f(unsigned short u){
    return __builtin_bit_cast(float, (unsigned int)u << 16);
}
__device__ inline unsigned int pack_bf16_trunc(float lo, float hi){
    return __builtin_amdgcn_perm(__builtin_bit_cast(unsigned int, hi),
                                 __builtin_bit_cast(unsigned int, lo), 0x07060302u);
}
__device__ inline float exp2_fast(float x){ return __builtin_amdgcn_exp2f(x); }

// ---------------------------------------------------------------------------
// K0: x -> xdi (bf16, columns permuted inside each 32-block for single-MFMA PV)
// ---------------------------------------------------------------------------
__global__ void k_vint(const float* __restrict__ x, unsigned short* __restrict__ xdi){
    int tid = blockIdx.x*256 + threadIdx.x;     // [row(12) | g(8)]
    int g   = tid & 255;
    int row = tid >> 8;
    int kgw = g & 3;
    int kv0 = (g >> 2) << 5;
    const float* src = x + (size_t)row*Wn + kv0 + 4*kgw;
    float4 a = *reinterpret_cast<const float4*>(src);
    float4 b = *reinterpret_cast<const float4*>(src + 16);
    union { unsigned short us[8]; uint4 v; } u;
    u.us[0]=f2bf(a.x); u.us[1]=f2bf(a.y); u.us[2]=f2bf(a.z); u.us[3]=f2bf(a.w);
    u.us[4]=f2bf(b.x); u.us[5]=f2bf(b.y); u.us[6]=f2bf(b.z); u.us[7]=f2bf(b.w);
    *reinterpret_cast<uint4*>(xdi + (size_t)row*Wn + kv0 + 8*kgw) = u.v;
}

// ---------------------------------------------------------------------------
// K1: x -> xT (K operand, unscaled) and xQ (Q operand, scaled E^-0.5*log2e)
// ---------------------------------------------------------------------------
__global__ void k_xT(const float* __restrict__ x, unsigned short* __restrict__ xT,
                     unsigned short* __restrict__ xQ){
    const float qs = 0.03125f * 1.44269504088896340736f;
    int tid = blockIdx.x*256 + threadIdx.x;
    int w   = tid & (Wn-1);
    int dg  = (tid >> 11) & 7;
    int bh  = tid >> 14;
    const float* src = x + ((size_t)bh*Dh + dg*8)*Wn + w;
    union { unsigned short us[8]; uint4 v; } u, uq;
    #pragma unroll
    for (int i = 0; i < 8; i++){
        float f = src[(size_t)i*Wn];
        u.us[i]  = f2bf(f);
        uq.us[i] = f2bf(f * qs);
    }
    size_t off = ((size_t)bh*Wn + w)*Dh + dg*8;
    *reinterpret_cast<uint4*>(xT + off) = u.v;
    *reinterpret_cast<uint4*>(xQ + off) = uq.v;
}

// ---------------------------------------------------------------------------
// K2: M_d -> MT (bf16 transposed)
// ---------------------------------------------------------------------------
__global__ void k_MT(const float* __restrict__ M, unsigned short* __restrict__ MT){
    int tid = blockIdx.x*256 + threadIdx.x;  // [eg(7) | f(10)]
    int f  = tid & (E-1);
    int eg = tid >> 10;
    union { unsigned short us[8]; uint4 v; } u;
    #pragma unroll
    for (int i = 0; i < 8; i++) u.us[i] = f2bf(M[(size_t)(eg*8+i)*E + f]);
    *reinterpret_cast<uint4*>(MT + (size_t)f*E + eg*8) = u.v;
}

// ---------------------------------------------------------------------------
// K3: flash attention, no max-tracking, KV-split heavy blocks (additive
// partials), and REGISTER PING-PONG PREFETCH: next step's 8x16B K/V loads
// are issued before the current step's MFMA/exp chain, via a manually
// 2x-unrolled loop with named frag structs (no reg copies, static indexing).
// ---------------------------------------------------------------------------
struct KVf { bf16x8 k0a, k0b, k1a, k1b, v0, v1, v2, v3; };

__global__ __launch_bounds__(256) void k_attn(const unsigned short* __restrict__ xT,
                                              const unsigned short* __restrict__ xQ,
                                              const unsigned short* __restrict__ xdi,
                                              unsigned short* __restrict__ tws,
                                              unsigned short* __restrict__ pacc,
                                              float* __restrict__ pl){
    const int lane = threadIdx.x & 63;
    const int wv   = threadIdx.x >> 6;
    const int jl = lane & 15, kg = lane >> 4;
    const int bid = blockIdx.x >> 4;                // 0..95
    const int hg  = blockIdx.x & 15;
    const int bh  = hg*4 + wv;

    int qb, kvb, kve, half;
    bool diag, heavy;
    if (bid < 32){
        qb = 32 + bid; kvb = 0; kve = 1024; diag = false; heavy = true; half = 0;
    } else {
        int k = (bid - 32) >> 1;
        if (bid & 1){ qb = 31 - k; kvb = 0;    kve = qb*32; diag = true; heavy = false; half = 0; }
        else        { qb = 63 - k; kvb = 1024; kve = qb*32; diag = true; heavy = true;  half = 1; }
    }
    const int q0 = qb*32;
    const int last = diag ? kve : kve - 32;         // inclusive last step

    const bf16x8* xTr = reinterpret_cast<const bf16x8*>(xT + (size_t)bh*Wn*Dh);
    const bf16x8* xQr = reinterpret_cast<const bf16x8*>(xQ + (size_t)bh*Wn*Dh);
    const bf16x8* xdr = reinterpret_cast<const bf16x8*>(xdi + (size_t)bh*Dh*Wn);

    bf16x8 bq[2][2];
    #pragma unroll
    for (int jt = 0; jt < 2; jt++){
        bq[jt][0] = xQr[(q0+jt*16+jl)*8 + kg];
        bq[jt][1] = xQr[(q0+jt*16+jl)*8 + 4 + kg];
    }

    f32x4 acc[2][4] = {};
    float l[2] = {0.f, 0.f};

    auto load = [&](int kv0) -> KVf {
        KVf f;
        f.k0a = xTr[(kv0+jl)*8 + kg];
        f.k0b = xTr[(kv0+jl)*8 + 4 + kg];
        f.k1a = xTr[(kv0+16+jl)*8 + kg];
        f.k1b = xTr[(kv0+16+jl)*8 + 4 + kg];
        f.v0  = xdr[(0*16+jl)*(Wn/8) + (kv0 >> 3) + kg];
        f.v1  = xdr[(1*16+jl)*(Wn/8) + (kv0 >> 3) + kg];
        f.v2  = xdr[(2*16+jl)*(Wn/8) + (kv0 >> 3) + kg];
        f.v3  = xdr[(3*16+jl)*(Wn/8) + (kv0 >> 3) + kg];
        return f;
    };

    auto compute = [&](const KVf& f, int kv0){
        const bool dg = (kv0 == q0);                // diagonal (causal) step
        #pragma unroll
        for (int jt = 0; jt < 2; jt++){
            f32x4 s0 = {0,0,0,0}, s1 = {0,0,0,0};
            s0 = __builtin_amdgcn_mfma_f32_16x16x32_bf16(f.k0a, bq[jt][0], s0, 0,0,0);
            s0 = __builtin_amdgcn_mfma_f32_16x16x32_bf16(f.k0b, bq[jt][1], s0, 0,0,0);
            s1 = __builtin_amdgcn_mfma_f32_16x16x32_bf16(f.k1a, bq[jt][0], s1, 0,0,0);
            s1 = __builtin_amdgcn_mfma_f32_16x16x32_bf16(f.k1b, bq[jt][1], s1, 0,0,0);

            const int lim = dg ? (16*jt + jl) : 64;
            float p[8];
            #pragma unroll
            for (int r = 0; r < 4; r++){
                int c = 4*kg + r;
                float e0 = exp2_fast(s0[r]);
                float e1 = exp2_fast(s1[r]);
                p[r]   = (c      <= lim) ? e0 : 0.f;
                p[4+r] = (c + 16 <= lim) ? e1 : 0.f;
            }
            l[jt] += ((p[0]+p[1]) + (p[2]+p[3])) + ((p[4]+p[5]) + (p[6]+p[7]));

            union { bf16x8 v; unsigned int w[4]; } bp;
            bp.w[0] = pack_bf16_trunc(p[0], p[1]);
            bp.w[1] = pack_bf16_trunc(p[2], p[3]);
            bp.w[2] = pack_bf16_trunc(p[4], p[5]);
            bp.w[3] = pack_bf16_trunc(p[6], p[7]);

            acc[jt][0] = __builtin_amdgcn_mfma_f32_16x16x32_bf16(f.v0, bp.v, acc[jt][0], 0,0,0);
            acc[jt][1] = __builtin_amdgcn_mfma_f32_16x16x32_bf16(f.v1, bp.v, acc[jt][1], 0,0,0);
            acc[jt][2] = __builtin_amdgcn_mfma_f32_16x16x32_bf16(f.v2, bp.v, acc[jt][2], 0,0,0);
            acc[jt][3] = __builtin_amdgcn_mfma_f32_16x16x32_bf16(f.v3, bp.v, acc[jt][3], 0,0,0);
        }
    };

    // ---- ping-pong prefetch main loop (2x unrolled, no register copies)
    {
        KVf a = load(kvb);
        int kv0 = kvb;
        while (true){
            int kn = kv0 + 32 <= last ? kv0 + 32 : kv0;
            KVf b = load(kn);
            compute(a, kv0);
            kv0 += 32;
            if (kv0 > last) break;
            kn = kv0 + 32 <= last ? kv0 + 32 : kv0;
            a = load(kn);
            compute(b, kv0);
            kv0 += 32;
            if (kv0 > last) break;
        }
    }

    if (!heavy){
        // ---- light epilogue: reduce l, normalize, write tws
        #pragma unroll
        for (int jt = 0; jt < 2; jt++){
            float lj = l[jt];
            lj += __shfl_xor(lj, 16);
            lj += __shfl_xor(lj, 32);
            const float inv = 1.0f / lj;
            unsigned short* trow = tws + ((size_t)(bh >> 4)*Wn + q0 + jt*16 + jl)*E + (bh & 15)*Dh;
            #pragma unroll
            for (int dt = 0; dt < 4; dt++){
                union { unsigned short us[4]; ushort4 v; } o;
                #pragma unroll
                for (int r = 0; r < 4; r++) o.us[r] = f2bf(acc[jt][dt][r] * inv);
                *reinterpret_cast<ushort4*>(trow + dt*16 + 4*kg) = o.v;
            }
        }
    } else {
        // ---- heavy epilogue: write bf16 acc partial + f32 l partial
        const int qh = qb - 32;
        const size_t slot = (size_t)(bh*32 + qh)*2 + half;
        float l0 = l[0]; l0 += __shfl_xor(l0, 16); l0 += __shfl_xor(l0, 32);
        float l1 = l[1]; l1 += __shfl_xor(l1, 16); l1 += __shfl_xor(l1, 32);
        if (kg == 0){
            pl[slot*32 + jl]      = l0;
            pl[slot*32 + 16 + jl] = l1;
        }
        unsigned short* pa = pacc + slot*2048;
        #pragma unroll
        for (int jt = 0; jt < 2; jt++){
            #pragma unroll
            for (int dt = 0; dt < 4; dt++){
                union { unsigned short us[4]; ushort4 v; } o;
                #pragma unroll
                for (int r = 0; r < 4; r++) o.us[r] = f2bf(acc[jt][dt][r]);
                *reinterpret_cast<ushort4*>(pa + (jt*16+jl)*64 + dt*16 + 4*kg) = o.v;
            }
        }
    }
}

// ---------------------------------------------------------------------------
// K3b: combine the two KV-chunk partials of each heavy q-block, normalize,
// write tws. 2048 tiles; block=256 handles 4 tiles (64 thr/tile).
// ---------------------------------------------------------------------------
__global__ __launch_bounds__(256) void k_reduce(const unsigned short* __restrict__ pacc,
                                                const float* __restrict__ pl,
                                                unsigned short* __restrict__ tws){
    const int g  = blockIdx.x*4 + (threadIdx.x >> 6);   // tile 0..2047
    const int t  = threadIdx.x & 63;
    const int bh = g >> 5, qh = g & 31;
    const int q  = t >> 1;
    const int dbase = (t & 1)*32;
    const size_t slot0 = (size_t)(bh*32 + qh)*2;

    const float inv = 1.0f / (pl[slot0*32 + q] + pl[(slot0+1)*32 + q]);
    const unsigned short* a0 = pacc + slot0*2048 + q*64 + dbase;

    unsigned short* tw = tws + ((size_t)(bh >> 4)*Wn + (qh+32)*32 + q)*E + (bh & 15)*Dh + dbase;
    #pragma unroll
    for (int i = 0; i < 4; i++){
        union { uint4 v; unsigned short us[8]; } r0, r1, o;
        r0.v = *reinterpret_cast<const uint4*>(a0 + i*8);
        r1.v = *reinterpret_cast<const uint4*>(a0 + 2048 + i*8);
        #pragma unroll
        for (int j = 0; j < 8; j++)
            o.us[j] = f2bf((bf2f(r0.us[j]) + bf2f(r1.us[j])) * inv);
        *reinterpret_cast<uint4*>(tw + i*8) = o.v;
    }
}

// ---------------------------------------------------------------------------
// K4: out[b][f][w] = sum_e MT[f][e] * t_ws[b][w][e] + b_d[f]
// 128x128 C-tile per block (4 waves x 64x64); register ping-pong prefetch
// over the K(=e) loop, fragments direct from L2/L3.
// ---------------------------------------------------------------------------
struct GF { bf16x8 am0, am1, am2, am3, bn0, bn1, bn2, bn3; };

__global__ __launch_bounds__(256) void k_gemm(const unsigned short* __restrict__ MT,
                                              const unsigned short* __restrict__ tws,
                                              const float* __restrict__ bd,
                                              float* __restrict__ out){
    const int lane = threadIdx.x & 63;
    const int wv   = threadIdx.x >> 6;
    const int jl = lane & 15, kg = lane >> 4;
    const int blk = blockIdx.x;
    const int b  = blk >> 7;          // 128 tiles per batch
    const int t2 = blk & 127;
    const int f0 = (t2 >> 4)*128 + (wv >> 1)*64;
    const int w0 = (t2 & 15)*128 + (wv &  1)*64;

    const bf16x8* Ar = reinterpret_cast<const bf16x8*>(MT);
    const bf16x8* Br = reinterpret_cast<const bf16x8*>(tws + (size_t)b*Wn*E);

    auto load = [&](int e0) -> GF {
        GF g;
        g.am0 = Ar[(size_t)(f0 + 0*16 + jl)*(E/8) + (e0 >> 3) + kg];
        g.am1 = Ar[(size_t)(f0 + 1*16 + jl)*(E/8) + (e0 >> 3) + kg];
        g.am2 = Ar[(size_t)(f0 + 2*16 + jl)*(E/8) + (e0 >> 3) + kg];
        g.am3 = Ar[(size_t)(f0 + 3*16 + jl)*(E/8) + (e0 >> 3) + kg];
        g.bn0 = Br[(size_t)(w0 + 0*16 + jl)*(E/8) + (e0 >> 3) + kg];
        g.bn1 = Br[(size_t)(w0 + 1*16 + jl)*(E/8) + (e0 >> 3) + kg];
        g.bn2 = Br[(size_t)(w0 + 2*16 + jl)*(E/8) + (e0 >> 3) + kg];
        g.bn3 = Br[(size_t)(w0 + 3*16 + jl)*(E/8) + (e0 >> 3) + kg];
        return g;
    };

    f32x4 acc[4][4] = {};
    auto compute = [&](const GF& g){
        const bf16x8 am[4] = {g.am0, g.am1, g.am2, g.am3};
        const bf16x8 bn[4] = {g.bn0, g.bn1, g.bn2, g.bn3};
        #pragma unroll
        for (int i = 0; i < 4; i++)
            #pragma unroll
            for (int j = 0; j < 4; j++)
                acc[i][j] = __builtin_amdgcn_mfma_f32_16x16x32_bf16(am[i], bn[j], acc[i][j], 0,0,0);
    };

    {
        GF a = load(0);
        int e0 = 0;
        while (true){
            GF bb = load(e0 + 32 < E ? e0 + 32 : e0);
            compute(a);
            e0 += 32;
            if (e0 >= E) break;
            a = load(e0 + 32 < E ? e0 + 32 : e0);
            compute(bb);
            e0 += 32;
            if (e0 >= E) break;
        }
    }

    #pragma unroll
    for (int i = 0; i < 4; i++){
        float bias[4];
        #pragma unroll
        for (int r = 0; r < 4; r++) bias[r] = bd[f0 + i*16 + 4*kg + r];
        #pragma unroll
        for (int j = 0; j < 4; j++){
            #pragma unroll
            for (int r = 0; r < 4; r++){
                out[((size_t)b*E + f0 + i*16 + 4*kg + r)*Wn + w0 + j*16 + jl]
                    = acc[i][j][r] + bias[r];
            }
        }
    }
}

// ---------------------------------------------------------------------------
extern "C" void kernel_launch(void* const* d_in, const int* in_sizes, int n_in,
                              void* d_out, int out_size, void* d_ws, size_t ws_size,
                              hipStream_t stream) {
    const float* x  = (const float*)d_in[0];   // (B,E,W)
    const float* Md = (const float*)d_in[1];   // (E,E)
    const float* bd = (const float*)d_in[2];   // (E,)
    float* out = (float*)d_out;                // (B,E,W)

    char* ws = (char*)d_ws;
    unsigned short* xT   = (unsigned short*)(ws);                    // 16 MB
    unsigned short* xQ   = (unsigned short*)(ws + (16u << 20));      // 16 MB
    unsigned short* xdi  = (unsigned short*)(ws + (32u << 20));      // 16 MB
    unsigned short* MT   = (unsigned short*)(ws + (48u << 20));      //  2 MB
    unsigned short* tws  = (unsigned short*)(ws + (50u << 20));      // 16 MB
    float*          pl   = (float*)(ws + (66u << 20));               // 512 KB
    unsigned short* pacc = (unsigned short*)(ws + (67u << 20));      // 16 MB

    hipLaunchKernelGGL(k_vint,   dim3(4096), dim3(256), 0, stream, x, xdi);
    hipLaunchKernelGGL(k_xT,     dim3(4096), dim3(256), 0, stream, x, xT, xQ);
    hipLaunchKernelGGL(k_MT,     dim3(512),  dim3(256), 0, stream, Md, MT);
    hipLaunchKernelGGL(k_attn,   dim3(96*16), dim3(256), 0, stream, xT, xQ, xdi, tws, pacc, pl);
    hipLaunchKernelGGL(k_reduce, dim3(512),  dim3(256), 0, stream, pacc, pl, tws);
    hipLaunchKernelGGL(k_gemm,   dim3(B*(E/128)*(Wn/128)), dim3(256), 0, stream, MT, tws, bd, out);
}